// Round 12
// baseline (31.047 us; speedup 1.0000x reference)
//
#include <hip/hip_runtime.h>

#define NB 32
#define NT 128
#define NI 64
#define NH 512
#define HGB 32   // h per cur block
#define PSTR 45  // u64 stride per i in LDS pair table
typedef unsigned long long u64;
typedef unsigned int u32;
typedef unsigned char u8;

// ---- LDS layout (bytes) ----
// P    : 64*45*8  = 23040   byte-train pair table
// BUF  : 33280             phase A: xl[128][65] floats; phase C: Wl4 (16 KB)
// KL   : 2048               packed koff  (per-synapse, = (50-d0)>>2)
// RL   : 2048               packed r8    (pre-shifted, = ((50-d0)&3)<<3)
// MM   : 64*2*8   = 1024    spike bitmasks
#define OFF_P 0
#define OFF_BUF 23040
#define OFF_WL 23040
#define OFF_KL (23040 + 33280)
#define OFF_RL (OFF_KL + 2048)
#define OFF_MM (OFF_RL + 2048)
#define SMEM_BYTES (OFF_MM + 1024)

// ---------------- K0: currents only (no LIF tail) ----------------
// grid (b:32, hg:16); block 1024 = 16 waves.
// Lane = (hl:32, ch:2); c = wv*2+ch is the 4-t chunk (0..31).
// Phase C: R6/R9's proven body (FP expression graph FROZEN - R5/R8 showed
// any dataflow restructure flips near-threshold spikes; R10 SGB null).
// New vs R11: per-wave s_sleep stagger before phase C. All 16 waves leave
// the barrier in lockstep and run identical code -> DS bursts collide
// (convoy: DS saturates while VALU idles, then swap). Staggering wave wv
// by wv*64cy interleaves the pipes. Wave-uniform scalar sleeps, zero FP
// effect -> bit-identical output by construction.
__global__ __launch_bounds__(1024, 4) void cur_kernel(
    const float* __restrict__ x, const float* __restrict__ w_ih,
    const float* __restrict__ draw, float4* __restrict__ Ig) {
  __shared__ char smem[SMEM_BYTES];
  u64* P = (u64*)(smem + OFF_P);
  float* xl = (float*)(smem + OFF_BUF);     // [NT][NI+1]
  float4* Wl4 = (float4*)(smem + OFF_WL);   // [(NI/2)*HGB] (w0a,w1a,w0b,w1b)
  u32* Klw = (u32*)(smem + OFF_KL);         // [(NI/4)*HGB] packed koff bytes
  u32* Rlw = (u32*)(smem + OFF_RL);         // [(NI/4)*HGB] packed r8 bytes
  u64* Mm = (u64*)(smem + OFF_MM);          // [NI][2]

  const int tid = threadIdx.x;
  const int lane = tid & 63;
  const int wv = tid >> 6;                 // 0..15
  const int hl = lane & 31;
  const int ch = lane >> 5;
  const int c = wv * 2 + ch;               // t-chunk 0..31 (4 t each)
  const int b = blockIdx.x;
  const int hg = blockIdx.y;

  // ---- Hoisted B2 global loads (issue before any barrier) ----
  float4 wv4h = make_float4(0.f, 0.f, 0.f, 0.f);
  float4 rv4h = make_float4(0.f, 0.f, 0.f, 0.f);
  if (tid < 512) {
    int i4 = tid & 15, hh = tid >> 4;  // hh = h-local 0..31
    int h = hg * HGB + hh;
    wv4h = *((const float4*)(w_ih + (size_t)h * NI) + i4);
    rv4h = *((const float4*)(draw + (size_t)h * NI) + i4);
  }

  // ---- Phase A: stage x[b] -> xl[t][i] (coalesced float4 reads) ----
  {
    const float* xb = x + (size_t)b * (NT * NI);
    #pragma unroll
    for (int k2 = 0; k2 < 2; ++k2) {
      int e = (k2 * 1024 + tid) * 4;
      float4 v = *(const float4*)(xb + e);
      float* row = xl + (e >> 6) * (NI + 1) + (e & 63);
      row[0] = v.x; row[1] = v.y; row[2] = v.z; row[3] = v.w;
    }
  }
  __syncthreads();

  // ---- Phase A2: ballot-pack into per-i 128-bit masks ----
  #pragma unroll
  for (int j = 0; j < 8; ++j) {
    int idx = wv * 8 + j;  // 0..127 = i*2 + h2
    int i = idx >> 1;
    int h2 = idx & 1;
    u64 m = __ballot(xl[(h2 * 64 + lane) * (NI + 1) + i] != 0.0f);
    if (lane == 0) Mm[i * 2 + h2] = m;
  }
  __syncthreads();

  // ---- Phase B: masks -> zero-padded byte-train pair table ----
  // word w (0..45): bytes 4w..4w+3; byte 52+t = spike[t]; pads zero.
  for (int idx = tid; idx < NI * PSTR; idx += 1024) {
    int i = idx / PSTR;
    int k = idx - i * PSTR;
    u64 m0 = Mm[i * 2], m1 = Mm[i * 2 + 1];
    u32 lo = 0, hi = 0;
    if (k >= 13) {
      int t = (k - 13) * 4;
      u32 nib = (u32)(((t < 64) ? (m0 >> t) : (m1 >> (t - 64))) & 15);
      lo = (nib * 0x00204081u) & 0x01010101u;
    }
    if (k + 1 >= 13 && k + 1 < 45) {
      int t = (k - 12) * 4;
      u32 nib = (u32)(((t < 64) ? (m0 >> t) : (m1 >> (t - 64))) & 15);
      hi = (nib * 0x00204081u) & 0x01010101u;
    }
    P[idx] = ((u64)hi << 32) | lo;
  }

  // ---- Phase B2: per-synapse prep (paired weights + koff/r8) ----
  // koff = (50-i0)>>2, r8 = ((50-i0)&3)<<3 are exact rewrites of the old
  // in-loop p/k/r8 arithmetic (c*4 == 0 mod 4, 0 <= 50-i0 <= 50).
  // Uses the globals hoisted to kernel entry; math identical to R6/R9.
  if (tid < 512) {
    int i4 = tid & 15, hh = tid >> 4;  // hh = h-local 0..31
    float wa[4] = {wv4h.x, wv4h.y, wv4h.z, wv4h.w};
    float ra[4] = {rv4h.x, rv4h.y, rv4h.z, rv4h.w};
    float w0s[4], w1s[4];
    u32 kword = 0, rword = 0;
    #pragma unroll
    for (int jj = 0; jj < 4; ++jj) {
      float sig = 1.0f / (1.0f + expf(-ra[jj]));
      float d = sig * 50.0f;
      float d0f = floorf(d);
      float frac = d - d0f;
      int i0 = (int)d0f;
      float w0 = wa[jj] * (1.0f - frac);
      float w1 = wa[jj] * frac;
      if (i0 >= 50) { w0 += w1; w1 = 0.0f; i0 = 50; }  // safety fold
      w0s[jj] = w0; w1s[jj] = w1;
      int q = 50 - i0;                           // 0..50
      kword |= (u32)(q >> 2) << (8 * jj);        // 0..12
      rword |= (u32)((q & 3) << 3) << (8 * jj);  // 0/8/16/24
    }
    Wl4[(2 * i4) * HGB + hh]     = make_float4(w0s[0], w1s[0], w0s[1], w1s[1]);
    Wl4[(2 * i4 + 1) * HGB + hh] = make_float4(w0s[2], w1s[2], w0s[3], w1s[3]);
    Klw[i4 * HGB + hh] = kword;
    Rlw[i4 * HGB + hh] = rword;
  }
  __syncthreads();

  // ---- Desync waves: break the phase-C DS convoy (bit-safe) ----
  #pragma unroll 1
  for (int z = 0; z < wv; ++z) __builtin_amdgcn_s_sleep(1);

  // ---- Phase C: byte-window currents (4 t per thread) ----
  float acc[4];
  #pragma unroll
  for (int j = 0; j < 4; ++j) acc[j] = 0.0f;

  // Preload packed koff/r8 (32 VGPRs, simple unrolled loop = the pattern
  // that provably stayed in registers in R4/R6 preloads).
  u32 kall[16], rall[16];
  #pragma unroll
  for (int q = 0; q < 16; ++q) {
    kall[q] = Klw[q * HGB + hl];
    rall[q] = Rlw[q * HGB + hl];
  }
  const u64* Pc = P + c;  // per-thread base; entry index = i*PSTR + koff

#define TAPS(IDX, W0, W1, KO, R8)                              \
  do {                                                         \
    u64 A = Pc[(IDX) * PSTR + (KO)];                           \
    u64 s1 = A >> (R8);                                        \
    u32 a0 = (u32)s1, a1 = (u32)(s1 >> 32);                    \
    float f0 = (float)(a0 & 255u);                             \
    float f1 = (float)((a0 >> 8) & 255u);                      \
    float f2 = (float)((a0 >> 16) & 255u);                     \
    float f3 = (float)(a0 >> 24);                              \
    float f4 = (float)(a1 & 255u);                             \
    acc[0] += (W0) * f1 + (W1) * f0;                           \
    acc[1] += (W0) * f2 + (W1) * f1;                           \
    acc[2] += (W0) * f3 + (W1) * f2;                           \
    acc[3] += (W0) * f4 + (W1) * f3;                           \
  } while (0)

  #pragma unroll
  for (int i4 = 0; i4 < 16; ++i4) {
    u32 kw = kall[i4];
    u32 rw = rall[i4];
    float4 wa = Wl4[(2 * i4) * HGB + hl];
    float4 wb = Wl4[(2 * i4 + 1) * HGB + hl];
    TAPS(4 * i4 + 0, wa.x, wa.y, (kw & 255u), (rw & 255u));
    TAPS(4 * i4 + 1, wa.z, wa.w, ((kw >> 8) & 255u), ((rw >> 8) & 255u));
    TAPS(4 * i4 + 2, wb.x, wb.y, ((kw >> 16) & 255u), ((rw >> 16) & 255u));
    TAPS(4 * i4 + 3, wb.z, wb.w, (kw >> 24), (rw >> 24));
  }
#undef TAPS

  // ---- store currents to global, transposed: I[c][b][h] ----
  // Wave writes two contiguous 512B segments -> fully coalesced.
  Ig[((size_t)c * NB + b) * NH + hg * HGB + hl] =
      make_float4(acc[0], acc[1], acc[2], acc[3]);
}

// ---------------- K1: fused LIF scans + deterministic h-reduction ----------
// One block per b, 512 threads; thread tid scans h=tid (128-step chain).
// Ig is [c][b][h]: coalesced loads. New vs R11: 3-deep named-scalar load
// prefetch (cu/n1/n2/n3, fully unrolled static indices) to hide L2/L3
// latency; pure load reordering of read-only data - LIF expressions
// textually identical. Combine Pl[tid]+Pl[tid+256] and the 256-wide tree
// preserve the EXACT summation order of the proven version.
__global__ __launch_bounds__(512) void lifred_kernel(
    const float4* __restrict__ Ig, const float* __restrict__ w_read,
    const float* __restrict__ b_read, float* __restrict__ out) {
  const int b = blockIdx.x;
  const int tid = threadIdx.x;  // 0..511 = h
  const float wr = w_read[tid];
  const float br = b_read[0];

  float v = 0.0f;
  int ref = 0;
  float c0 = 0.f, c1 = 0.f, c2 = 0.f, c3 = 0.f;
  float4 cu = Ig[((size_t)0 * NB + b) * NH + tid];
  float4 n1 = Ig[((size_t)1 * NB + b) * NH + tid];
  float4 n2 = Ig[((size_t)2 * NB + b) * NH + tid];
  #pragma unroll
  for (int gq = 0; gq < NT / 4; ++gq) {
    float4 n3 = (gq + 3 < NT / 4)
        ? Ig[((size_t)(gq + 3) * NB + b) * NH + tid]
        : make_float4(0.f, 0.f, 0.f, 0.f);
    float Iv[4] = {cu.x, cu.y, cu.z, cu.w};
    #pragma unroll
    for (int j = 0; j < 4; ++j) {
      const int t = gq * 4 + j;  // compile-time constant
      float I = Iv[j];
      bool act = (ref <= 0);
      float vn = act ? (v + 0.1f * (I - v)) : v;
      bool spk = act && (vn >= 1.0f);
      v = spk ? 0.0f : vn;
      ref = spk ? 2 : (ref > 0 ? ref - 1 : 0);
      if ((t & 31) >= 8) {
        float inc = spk ? 1.0f : 0.0f;
        if (t < 32) c0 += inc;
        else if (t < 64) c1 += inc;
        else if (t < 96) c2 += inc;
        else c3 += inc;
      }
    }
    cu = n1; n1 = n2; n2 = n3;
  }
  float4 pv = make_float4(c0 * wr, c1 * wr, c2 * wr, c3 * wr);

  __shared__ float4 Pl[512];
  __shared__ float4 red[256];
  Pl[tid] = pv;
  __syncthreads();
  if (tid < 256) {
    float4 a = Pl[tid], d2 = Pl[tid + 256];
    red[tid] = make_float4(a.x + d2.x, a.y + d2.y, a.z + d2.z, a.w + d2.w);
  }
  __syncthreads();
  for (int off = 128; off > 0; off >>= 1) {
    if (tid < off) {
      float4 a = red[tid], d2 = red[tid + off];
      red[tid] = make_float4(a.x + d2.x, a.y + d2.y, a.z + d2.z, a.w + d2.w);
    }
    __syncthreads();
  }
  if (tid == 0) {
    float4 r = red[0];
    out[b * 4 + 0] = r.x + br;
    out[b * 4 + 1] = r.y + br;
    out[b * 4 + 2] = r.z + br;
    out[b * 4 + 3] = r.w + br;
  }
}

extern "C" void kernel_launch(void* const* d_in, const int* in_sizes, int n_in,
                              void* d_out, int out_size, void* d_ws, size_t ws_size,
                              hipStream_t stream) {
  const float* x      = (const float*)d_in[0];  // [B,T,NIN]
  const float* w_ih   = (const float*)d_in[1];  // [H,NIN]
  const float* draw   = (const float*)d_in[2];  // [H,NIN]
  const float* w_read = (const float*)d_in[3];  // [H]
  const float* b_read = (const float*)d_in[4];  // scalar

  char* ws = (char*)d_ws;
  float4* Ig  = (float4*)ws;                    // 8 MB currents [c][b][h]
  float*  out = (float*)d_out;

  cur_kernel<<<dim3(NB, NH / HGB), dim3(1024), 0, stream>>>(
      x, w_ih, draw, Ig);
  lifred_kernel<<<dim3(NB), dim3(512), 0, stream>>>(
      Ig, w_read, b_read, out);
}

// Round 13
// 30.720 us; speedup vs baseline: 1.0106x; 1.0106x over previous
//
#include <hip/hip_runtime.h>

#define NB 32
#define NT 128
#define NI 64
#define NH 512
#define HGB 32   // h per cur block
#define PSTR 45  // u64 stride per i in LDS pair table
typedef unsigned long long u64;
typedef unsigned int u32;
typedef unsigned char u8;

// ---- LDS layout (bytes) ----
// P    : 64*45*8  = 23040   byte-train pair table
// BUF  : 33280             phase A: xl[128][65] floats; phase C: Wl4 (16 KB)
// KR   : 16*32*8  = 4096    merged u64 (lo=kword, hi=rword)
// MM   : 64*2*8   = 1024    spike bitmasks
#define OFF_P 0
#define OFF_BUF 23040
#define OFF_WL 23040
#define OFF_KR (23040 + 33280)
#define OFF_MM (OFF_KR + 4096)
#define SMEM_BYTES (OFF_MM + 1024)

// ---------------- K0: currents only (no LIF tail) ----------------
// grid (b:32, hg:16); block 1024 = 16 waves.
// Lane = (hl:32, ch:2); c = wv*2+ch is the 4-t chunk (0..31).
// Phase C: R6/R9/R11's proven body (FP expression graph FROZEN - R5/R8
// showed any dataflow restructure flips near-threshold spikes; R10 SGB
// null; R12 stagger null). New vs R11: Klw/Rlw merged into one u64 KRl
// table -> phase-C preload is 16 ds_read_b64 instead of 32 ds_read_b32;
// kw/rw extraction is free (u64 register halves). Integer packing only -
// the TAPS loop and every float expression are textually identical to
// R11 -> bit-identical output.
__global__ __launch_bounds__(1024, 4) void cur_kernel(
    const float* __restrict__ x, const float* __restrict__ w_ih,
    const float* __restrict__ draw, float4* __restrict__ Ig) {
  __shared__ char smem[SMEM_BYTES];
  u64* P = (u64*)(smem + OFF_P);
  float* xl = (float*)(smem + OFF_BUF);     // [NT][NI+1]
  float4* Wl4 = (float4*)(smem + OFF_WL);   // [(NI/2)*HGB] (w0a,w1a,w0b,w1b)
  u64* KRl = (u64*)(smem + OFF_KR);         // [(NI/4)*HGB] lo=kword hi=rword
  u64* Mm = (u64*)(smem + OFF_MM);          // [NI][2]

  const int tid = threadIdx.x;
  const int lane = tid & 63;
  const int wv = tid >> 6;                 // 0..15
  const int hl = lane & 31;
  const int ch = lane >> 5;
  const int c = wv * 2 + ch;               // t-chunk 0..31 (4 t each)
  const int b = blockIdx.x;
  const int hg = blockIdx.y;

  // ---- Hoisted B2 global loads (issue before any barrier) ----
  float4 wv4h = make_float4(0.f, 0.f, 0.f, 0.f);
  float4 rv4h = make_float4(0.f, 0.f, 0.f, 0.f);
  if (tid < 512) {
    int i4 = tid & 15, hh = tid >> 4;  // hh = h-local 0..31
    int h = hg * HGB + hh;
    wv4h = *((const float4*)(w_ih + (size_t)h * NI) + i4);
    rv4h = *((const float4*)(draw + (size_t)h * NI) + i4);
  }

  // ---- Phase A: stage x[b] -> xl[t][i] (coalesced float4 reads) ----
  {
    const float* xb = x + (size_t)b * (NT * NI);
    #pragma unroll
    for (int k2 = 0; k2 < 2; ++k2) {
      int e = (k2 * 1024 + tid) * 4;
      float4 v = *(const float4*)(xb + e);
      float* row = xl + (e >> 6) * (NI + 1) + (e & 63);
      row[0] = v.x; row[1] = v.y; row[2] = v.z; row[3] = v.w;
    }
  }
  __syncthreads();

  // ---- Phase A2: ballot-pack into per-i 128-bit masks ----
  #pragma unroll
  for (int j = 0; j < 8; ++j) {
    int idx = wv * 8 + j;  // 0..127 = i*2 + h2
    int i = idx >> 1;
    int h2 = idx & 1;
    u64 m = __ballot(xl[(h2 * 64 + lane) * (NI + 1) + i] != 0.0f);
    if (lane == 0) Mm[i * 2 + h2] = m;
  }
  __syncthreads();

  // ---- Phase B: masks -> zero-padded byte-train pair table ----
  // word w (0..45): bytes 4w..4w+3; byte 52+t = spike[t]; pads zero.
  for (int idx = tid; idx < NI * PSTR; idx += 1024) {
    int i = idx / PSTR;
    int k = idx - i * PSTR;
    u64 m0 = Mm[i * 2], m1 = Mm[i * 2 + 1];
    u32 lo = 0, hi = 0;
    if (k >= 13) {
      int t = (k - 13) * 4;
      u32 nib = (u32)(((t < 64) ? (m0 >> t) : (m1 >> (t - 64))) & 15);
      lo = (nib * 0x00204081u) & 0x01010101u;
    }
    if (k + 1 >= 13 && k + 1 < 45) {
      int t = (k - 12) * 4;
      u32 nib = (u32)(((t < 64) ? (m0 >> t) : (m1 >> (t - 64))) & 15);
      hi = (nib * 0x00204081u) & 0x01010101u;
    }
    P[idx] = ((u64)hi << 32) | lo;
  }

  // ---- Phase B2: per-synapse prep (paired weights + merged k/r word) ----
  // koff = (50-i0)>>2, r8 = ((50-i0)&3)<<3 are exact rewrites of the old
  // in-loop p/k/r8 arithmetic (c*4 == 0 mod 4, 0 <= 50-i0 <= 50).
  if (tid < 512) {
    int i4 = tid & 15, hh = tid >> 4;  // hh = h-local 0..31
    float wa[4] = {wv4h.x, wv4h.y, wv4h.z, wv4h.w};
    float ra[4] = {rv4h.x, rv4h.y, rv4h.z, rv4h.w};
    float w0s[4], w1s[4];
    u32 kword = 0, rword = 0;
    #pragma unroll
    for (int jj = 0; jj < 4; ++jj) {
      float sig = 1.0f / (1.0f + expf(-ra[jj]));
      float d = sig * 50.0f;
      float d0f = floorf(d);
      float frac = d - d0f;
      int i0 = (int)d0f;
      float w0 = wa[jj] * (1.0f - frac);
      float w1 = wa[jj] * frac;
      if (i0 >= 50) { w0 += w1; w1 = 0.0f; i0 = 50; }  // safety fold
      w0s[jj] = w0; w1s[jj] = w1;
      int q = 50 - i0;                           // 0..50
      kword |= (u32)(q >> 2) << (8 * jj);        // 0..12
      rword |= (u32)((q & 3) << 3) << (8 * jj);  // 0/8/16/24
    }
    Wl4[(2 * i4) * HGB + hh]     = make_float4(w0s[0], w1s[0], w0s[1], w1s[1]);
    Wl4[(2 * i4 + 1) * HGB + hh] = make_float4(w0s[2], w1s[2], w0s[3], w1s[3]);
    KRl[i4 * HGB + hh] = ((u64)rword << 32) | (u64)kword;
  }
  __syncthreads();

  // ---- Phase C: byte-window currents (4 t per thread) ----
  float acc[4];
  #pragma unroll
  for (int j = 0; j < 4; ++j) acc[j] = 0.0f;

  // Preload merged koff/r8 words (16 x ds_read_b64 -> 32 VGPRs; simple
  // unrolled loop = the pattern that provably stayed in registers).
  u64 krall[16];
  #pragma unroll
  for (int q = 0; q < 16; ++q) krall[q] = KRl[q * HGB + hl];
  const u64* Pc = P + c;  // per-thread base; entry index = i*PSTR + koff

#define TAPS(IDX, W0, W1, KO, R8)                              \
  do {                                                         \
    u64 A = Pc[(IDX) * PSTR + (KO)];                           \
    u64 s1 = A >> (R8);                                        \
    u32 a0 = (u32)s1, a1 = (u32)(s1 >> 32);                    \
    float f0 = (float)(a0 & 255u);                             \
    float f1 = (float)((a0 >> 8) & 255u);                      \
    float f2 = (float)((a0 >> 16) & 255u);                     \
    float f3 = (float)(a0 >> 24);                              \
    float f4 = (float)(a1 & 255u);                             \
    acc[0] += (W0) * f1 + (W1) * f0;                           \
    acc[1] += (W0) * f2 + (W1) * f1;                           \
    acc[2] += (W0) * f3 + (W1) * f2;                           \
    acc[3] += (W0) * f4 + (W1) * f3;                           \
  } while (0)

  #pragma unroll
  for (int i4 = 0; i4 < 16; ++i4) {
    u32 kw = (u32)krall[i4];
    u32 rw = (u32)(krall[i4] >> 32);
    float4 wa = Wl4[(2 * i4) * HGB + hl];
    float4 wb = Wl4[(2 * i4 + 1) * HGB + hl];
    TAPS(4 * i4 + 0, wa.x, wa.y, (kw & 255u), (rw & 255u));
    TAPS(4 * i4 + 1, wa.z, wa.w, ((kw >> 8) & 255u), ((rw >> 8) & 255u));
    TAPS(4 * i4 + 2, wb.x, wb.y, ((kw >> 16) & 255u), ((rw >> 16) & 255u));
    TAPS(4 * i4 + 3, wb.z, wb.w, (kw >> 24), (rw >> 24));
  }
#undef TAPS

  // ---- store currents to global, transposed: I[c][b][h] ----
  // Wave writes two contiguous 512B segments -> fully coalesced.
  Ig[((size_t)c * NB + b) * NH + hg * HGB + hl] =
      make_float4(acc[0], acc[1], acc[2], acc[3]);
}

// ---------------- K1: fused LIF scans + deterministic h-reduction ----------
// One block per b, 512 threads; thread tid scans h=tid (128-step chain).
// Ig is [c][b][h]: at each gq the 512 threads read 512 consecutive float4s
// -> fully coalesced. Combine Pl[tid] + Pl[tid+256] and the 256-wide tree
// preserve the EXACT summation order of the proven version.
__global__ __launch_bounds__(512) void lifred_kernel(
    const float4* __restrict__ Ig, const float* __restrict__ w_read,
    const float* __restrict__ b_read, float* __restrict__ out) {
  const int b = blockIdx.x;
  const int tid = threadIdx.x;  // 0..511 = h
  const float wr = w_read[tid];
  const float br = b_read[0];

  float v = 0.0f;
  int ref = 0;
  float c0 = 0.f, c1 = 0.f, c2 = 0.f, c3 = 0.f;
  float4 cur = Ig[(size_t)b * NH + tid];  // gq = 0
  #pragma unroll
  for (int gq = 0; gq < NT / 4; ++gq) {
    float4 nxt = (gq < NT / 4 - 1)
        ? Ig[((size_t)(gq + 1) * NB + b) * NH + tid]
        : make_float4(0.f, 0.f, 0.f, 0.f);
    float Iv[4] = {cur.x, cur.y, cur.z, cur.w};
    #pragma unroll
    for (int j = 0; j < 4; ++j) {
      const int t = gq * 4 + j;  // compile-time constant
      float I = Iv[j];
      bool act = (ref <= 0);
      float vn = act ? (v + 0.1f * (I - v)) : v;
      bool spk = act && (vn >= 1.0f);
      v = spk ? 0.0f : vn;
      ref = spk ? 2 : (ref > 0 ? ref - 1 : 0);
      if ((t & 31) >= 8) {
        float inc = spk ? 1.0f : 0.0f;
        if (t < 32) c0 += inc;
        else if (t < 64) c1 += inc;
        else if (t < 96) c2 += inc;
        else c3 += inc;
      }
    }
    cur = nxt;
  }
  float4 pv = make_float4(c0 * wr, c1 * wr, c2 * wr, c3 * wr);

  __shared__ float4 Pl[512];
  __shared__ float4 red[256];
  Pl[tid] = pv;
  __syncthreads();
  if (tid < 256) {
    float4 a = Pl[tid], d2 = Pl[tid + 256];
    red[tid] = make_float4(a.x + d2.x, a.y + d2.y, a.z + d2.z, a.w + d2.w);
  }
  __syncthreads();
  for (int off = 128; off > 0; off >>= 1) {
    if (tid < off) {
      float4 a = red[tid], d2 = red[tid + off];
      red[tid] = make_float4(a.x + d2.x, a.y + d2.y, a.z + d2.z, a.w + d2.w);
    }
    __syncthreads();
  }
  if (tid == 0) {
    float4 r = red[0];
    out[b * 4 + 0] = r.x + br;
    out[b * 4 + 1] = r.y + br;
    out[b * 4 + 2] = r.z + br;
    out[b * 4 + 3] = r.w + br;
  }
}

extern "C" void kernel_launch(void* const* d_in, const int* in_sizes, int n_in,
                              void* d_out, int out_size, void* d_ws, size_t ws_size,
                              hipStream_t stream) {
  const float* x      = (const float*)d_in[0];  // [B,T,NIN]
  const float* w_ih   = (const float*)d_in[1];  // [H,NIN]
  const float* draw   = (const float*)d_in[2];  // [H,NIN]
  const float* w_read = (const float*)d_in[3];  // [H]
  const float* b_read = (const float*)d_in[4];  // scalar

  char* ws = (char*)d_ws;
  float4* Ig  = (float4*)ws;                    // 8 MB currents [c][b][h]
  float*  out = (float*)d_out;

  cur_kernel<<<dim3(NB, NH / HGB), dim3(1024), 0, stream>>>(
      x, w_ih, draw, Ig);
  lifred_kernel<<<dim3(NB), dim3(512), 0, stream>>>(
      Ig, w_read, b_read, out);
}